// Round 12
// baseline (90.906 us; speedup 1.0000x reference)
//
#include <hip/hip_runtime.h>
#include <math.h>

#define PP 8192
#define DD 4096
#define NTOT 32768           // B * P
#define K_LOW 29490          // floor(0.9 * (NTOT-1))
#define NBINS 8192           // bucket = bits(|a|) >> 18
#define SCALE 1048576.0f     // 2^20 fixed-point for spmv accumulation
#define INV_SCALE (1.0f / 1048576.0f)
#define MSCALE 262144.0f     // 2^18 fixed-point for mean-sum accumulation
#define INV_MSCALE (1.0f / 262144.0f)
#define LIST_CAP 3072
#define NPB 256              // spmv blocks (= partials)

__device__ __forceinline__ float dot4(float4 w, float4 v) {
  return fmaf(w.x, v.x, fmaf(w.y, v.y, fmaf(w.z, v.z, w.w * v.w)));
}

// ---------------- Kernel 1: a = x @ W^T + b (R4-proven shape) ----------------
// 1024 blocks x 256 thr, 2 rows/wave, LB(256,4). First blocks zero hist/acc.
__global__ __launch_bounds__(256, 4) void gemm_kernel(const float* __restrict__ x,
                                                      const float* __restrict__ W,
                                                      const float* __restrict__ bias,
                                                      float* __restrict__ a,
                                                      unsigned* __restrict__ hist,
                                                      int* __restrict__ acc) {
  if (blockIdx.x < 32) {
    hist[blockIdx.x * 256 + threadIdx.x] = 0u;
  } else if (blockIdx.x == 32 && threadIdx.x < 4) {
    acc[threadIdx.x] = 0;
  }
  const int wave = threadIdx.x >> 6;
  const int lane = threadIdx.x & 63;
  const int p0 = blockIdx.x * 8 + wave * 2;
  const float4* __restrict__ W0 = (const float4*)(W + (size_t)p0 * DD);
  const float4* __restrict__ W1 = W0 + (DD / 4);
  const float4* __restrict__ x4 = (const float4*)x;
  double a00 = 0.0, a01 = 0.0, a02 = 0.0, a03 = 0.0;
  double a10 = 0.0, a11 = 0.0, a12 = 0.0, a13 = 0.0;
  #pragma unroll 4
  for (int k = 0; k < 16; ++k) {
    const int i = lane + k * 64;
    float4 w0 = W0[i];
    float4 w1 = W1[i];
    float4 v0 = x4[i];
    float4 v1 = x4[1024 + i];
    float4 v2 = x4[2048 + i];
    float4 v3 = x4[3072 + i];
    a00 += (double)dot4(w0, v0);
    a01 += (double)dot4(w0, v1);
    a02 += (double)dot4(w0, v2);
    a03 += (double)dot4(w0, v3);
    a10 += (double)dot4(w1, v0);
    a11 += (double)dot4(w1, v1);
    a12 += (double)dot4(w1, v2);
    a13 += (double)dot4(w1, v3);
  }
  #pragma unroll
  for (int off = 32; off > 0; off >>= 1) {
    a00 += __shfl_down(a00, off);
    a01 += __shfl_down(a01, off);
    a02 += __shfl_down(a02, off);
    a03 += __shfl_down(a03, off);
    a10 += __shfl_down(a10, off);
    a11 += __shfl_down(a11, off);
    a12 += __shfl_down(a12, off);
    a13 += __shfl_down(a13, off);
  }
  if (lane == 0) {
    float b0 = bias[p0];
    float b1 = bias[p0 + 1];
    a[0 * PP + p0] = (float)a00 + b0;
    a[1 * PP + p0] = (float)a01 + b0;
    a[2 * PP + p0] = (float)a02 + b0;
    a[3 * PP + p0] = (float)a03 + b0;
    a[0 * PP + p0 + 1] = (float)a10 + b1;
    a[1 * PP + p0 + 1] = (float)a11 + b1;
    a[2 * PP + p0 + 1] = (float)a12 + b1;
    a[3 * PP + p0 + 1] = (float)a13 + b1;
  }
}

// ---------------- Kernel 2: LDS histogram + last-block threshold select (R11) ----------------
__global__ __launch_bounds__(1024) void hist_thr_kernel(const float* __restrict__ a,
                                                        unsigned* __restrict__ hist,
                                                        int* __restrict__ acc,
                                                        float* __restrict__ thr) {
  __shared__ union {
    unsigned h[NBINS];
    struct {
      unsigned scan[1024];
      unsigned list1[LIST_CAP];
      unsigned list2[LIST_CAP];
      unsigned n1, n2, b1, r1, b2, r2, vlo, vhi;
    } t;
  } sh;
  __shared__ int s_last;
  const int tid = threadIdx.x;

  #pragma unroll
  for (int j = 0; j < NBINS / 1024; ++j) sh.h[tid + j * 1024] = 0u;
  __syncthreads();
  const int base = blockIdx.x * 4096 + tid;
  #pragma unroll
  for (int k = 0; k < 4; ++k) {
    unsigned u = __float_as_uint(fabsf(a[base + k * 1024]));
    atomicAdd(&sh.h[u >> 18], 1u);
  }
  __syncthreads();
  #pragma unroll
  for (int j = 0; j < NBINS / 1024; ++j) {
    unsigned c = sh.h[tid + j * 1024];
    if (c) atomicAdd(&hist[tid + j * 1024], c);
  }

  __threadfence();
  __syncthreads();
  if (tid == 0) {
    unsigned d = atomicAdd((unsigned*)&acc[3], 1u);
    s_last = (d == 7u) ? 1 : 0;
  }
  __syncthreads();
  if (!s_last) return;
  __threadfence();

  const uint4* h4 = (const uint4*)hist;
  uint4 q0 = h4[tid * 2];
  uint4 q1 = h4[tid * 2 + 1];
  unsigned part = q0.x + q0.y + q0.z + q0.w + q1.x + q1.y + q1.z + q1.w;
  __syncthreads();
  sh.t.scan[tid] = part;
  if (tid == 0) { sh.t.n1 = 0; sh.t.n2 = 0; }
  __syncthreads();
  for (int off = 1; off < 1024; off <<= 1) {
    unsigned v = (tid >= off) ? sh.t.scan[tid - off] : 0u;
    __syncthreads();
    sh.t.scan[tid] += v;
    __syncthreads();
  }
  const unsigned incl = sh.t.scan[tid];
  const unsigned excl = incl - part;
  unsigned bins[8] = {q0.x, q0.y, q0.z, q0.w, q1.x, q1.y, q1.z, q1.w};
  if (excl <= (unsigned)K_LOW && (unsigned)K_LOW < incl) {
    unsigned r = (unsigned)K_LOW - excl, cum = 0;
    #pragma unroll
    for (int j = 0; j < 8; ++j) {
      if (cum + bins[j] > r) { sh.t.b1 = tid * 8 + j; sh.t.r1 = r - cum; break; }
      cum += bins[j];
    }
  }
  if (excl <= (unsigned)(K_LOW + 1) && (unsigned)(K_LOW + 1) < incl) {
    unsigned r = (unsigned)(K_LOW + 1) - excl, cum = 0;
    #pragma unroll
    for (int j = 0; j < 8; ++j) {
      if (cum + bins[j] > r) { sh.t.b2 = tid * 8 + j; sh.t.r2 = r - cum; break; }
      cum += bins[j];
    }
  }
  __syncthreads();
  const unsigned b1 = sh.t.b1, r1 = sh.t.r1, b2 = sh.t.b2, r2 = sh.t.r2;
  for (int i = tid; i < NTOT; i += 1024) {
    unsigned u = __float_as_uint(fabsf(a[i]));
    unsigned bk = u >> 18;
    if (bk == b1) {
      unsigned idx = atomicAdd(&sh.t.n1, 1u);
      if (idx < LIST_CAP) sh.t.list1[idx] = u;
    } else if (bk == b2) {
      unsigned idx = atomicAdd(&sh.t.n2, 1u);
      if (idx < LIST_CAP) sh.t.list2[idx] = u;
    }
  }
  __syncthreads();
  const unsigned m1 = min(sh.t.n1, (unsigned)LIST_CAP);
  const unsigned m2 = min(sh.t.n2, (unsigned)LIST_CAP);
  for (unsigned i = tid; i < m1; i += 1024) {
    unsigned ui = sh.t.list1[i];
    unsigned ltc = 0, eqb = 0;
    for (unsigned j = 0; j < m1; ++j) {
      unsigned uj = sh.t.list1[j];
      ltc += (uj < ui) ? 1u : 0u;
      eqb += ((uj == ui) && (j < i)) ? 1u : 0u;
    }
    unsigned rk = ltc + eqb;
    if (rk == r1) sh.t.vlo = ui;
    if (b2 == b1 && rk == r2) sh.t.vhi = ui;
  }
  if (b2 != b1) {
    for (unsigned i = tid; i < m2; i += 1024) {
      unsigned ui = sh.t.list2[i];
      unsigned ltc = 0, eqb = 0;
      for (unsigned j = 0; j < m2; ++j) {
        unsigned uj = sh.t.list2[j];
        ltc += (uj < ui) ? 1u : 0u;
        eqb += ((uj == ui) && (j < i)) ? 1u : 0u;
      }
      if (ltc + eqb == r2) sh.t.vhi = ui;
    }
  }
  __syncthreads();
  if (tid == 0) {
    double dlo = (double)__uint_as_float(sh.t.vlo);
    double dhi = (double)__uint_as_float(sh.t.vhi);
    double idx = 0.9 * (double)(NTOT - 1);
    double g = idx - floor(idx);
    thr[0] = (float)(dlo + g * (dhi - dlo));
  }
}

// ---------------- Kernel 3: COO SpMV -> int partials (NO global atomics) ----------------
// R11-lesson candidate: the 2.1M-RMW global merge (256 adds/address) is the
// suspected hidden cost. Each block now writes its full s_rec slice as plain
// int4 stores; reduction happens in finalize.
__global__ __launch_bounds__(1024) void spmv_kernel(const float* __restrict__ vals,
                                                    const int* __restrict__ rows,
                                                    const int* __restrict__ cols,
                                                    const float* __restrict__ a,
                                                    const float* __restrict__ thr,
                                                    const float* __restrict__ sstate,
                                                    int* __restrict__ part,
                                                    int nc) {
  __shared__ float s_state[PP];
  __shared__ int s_rec[PP];
  const int tid = threadIdx.x;
  const float t = thr[0];
  for (int i = tid; i < PP; i += 1024) {
    float a0 = a[i];
    s_state[i] = (fabsf(a0) > t) ? a0 : 0.9f * sstate[i];
    s_rec[i] = 0;
  }
  __syncthreads();
  const int n4 = nc >> 2;
  const int stride = gridDim.x * 1024;
  const float4* __restrict__ v4 = (const float4*)vals;
  const int4* __restrict__ r4 = (const int4*)rows;
  const int4* __restrict__ c4 = (const int4*)cols;
  for (int i = blockIdx.x * 1024 + tid; i < n4; i += stride) {
    float4 v = v4[i];
    int4 r = r4[i];
    int4 c = c4[i];
    atomicAdd((unsigned*)&s_rec[r.x], (unsigned)__float2int_rn(v.x * s_state[c.x] * SCALE));
    atomicAdd((unsigned*)&s_rec[r.y], (unsigned)__float2int_rn(v.y * s_state[c.y] * SCALE));
    atomicAdd((unsigned*)&s_rec[r.z], (unsigned)__float2int_rn(v.z * s_state[c.z] * SCALE));
    atomicAdd((unsigned*)&s_rec[r.w], (unsigned)__float2int_rn(v.w * s_state[c.w] * SCALE));
  }
  if (blockIdx.x == 0 && tid < (nc - (n4 << 2))) {
    int i = (n4 << 2) + tid;
    atomicAdd((unsigned*)&s_rec[rows[i]],
              (unsigned)__float2int_rn(vals[i] * s_state[cols[i]] * SCALE));
  }
  __syncthreads();
  int4* dst = (int4*)(part + (size_t)blockIdx.x * PP);
  const int4* src = (const int4*)s_rec;
  for (int i = tid; i < PP / 4; i += 1024) dst[i] = src[i];
}

// ---------------- Kernel 4: reduce partials + GELU + scalars ----------------
// 256 blocks x 256 thr; block handles 32 rows. Thread (pl=tid&31, cls=tid>>5)
// sums b = cls, cls+8, ..., cls+248 -> LDS -> 8-way combine -> GELU + scalars.
// Coalesced: for fixed b, 32 consecutive threads read 32 consecutive ints.
__global__ __launch_bounds__(256) void finalize_kernel(const int* __restrict__ part,
                                                       const float* __restrict__ a,
                                                       const float* __restrict__ thr,
                                                       const float* __restrict__ sstate,
                                                       float* __restrict__ out,
                                                       int* __restrict__ acc) {
  __shared__ int s_red[32][9];
  const int tid = threadIdx.x;
  const int pl = tid & 31;
  const int cls = tid >> 5;
  const int p = blockIdx.x * 32 + pl;
  int s = 0;
  #pragma unroll 8
  for (int it = 0; it < 32; ++it) {
    s += part[(size_t)(it * 8 + cls) * PP + p];
  }
  s_red[pl][cls] = s;
  __syncthreads();
  const float t = thr[0];
  float lsum = 0.0f;
  unsigned lcnt = 0;
  if (tid < 32) {
    int tot = 0;
    #pragma unroll
    for (int c = 0; c < 8; ++c) tot += s_red[tid][c];
    float r = (float)tot * INV_SCALE;
    float a0 = a[p];
    bool m = fabsf(a0) > t;
    float st = m ? a0 : 0.9f * sstate[p];
    float v = st + 0.1f * r;
    float ns = 0.5f * v * (1.0f + erff(v * 0.70710678118654752440f));
    out[p] = ns;
    lsum = m ? ns : 0.0f;
    lcnt = m ? 1u : 0u;
  }
  // wave 0 (lanes 0..63) holds all 32 live values; other waves contribute 0
  #pragma unroll
  for (int off = 32; off > 0; off >>= 1) {
    lsum += __shfl_down(lsum, off);
    lcnt += __shfl_down(lcnt, off);
  }
  if (tid == 0) {
    atomicAdd((unsigned*)&acc[0], (unsigned)__float2int_rn(lsum * MSCALE));
    atomicAdd((unsigned*)&acc[1], lcnt);
    __threadfence();
    unsigned d = atomicAdd((unsigned*)&acc[2], 1u);
    if (d == (unsigned)(gridDim.x - 1)) {
      int sfix = (int)atomicAdd((unsigned*)&acc[0], 0u);
      int cnt = (int)atomicAdd((unsigned*)&acc[1], 0u);
      out[PP] = (float)cnt;
      out[PP + 1] = (cnt > 0) ? ((float)sfix * INV_MSCALE / (float)cnt) : 0.0f;
    }
  }
}

extern "C" void kernel_launch(void* const* d_in, const int* in_sizes, int n_in,
                              void* d_out, int out_size, void* d_ws, size_t ws_size,
                              hipStream_t stream) {
  const float* x      = (const float*)d_in[0];
  const float* W      = (const float*)d_in[1];
  const float* bias   = (const float*)d_in[2];
  const float* vals   = (const float*)d_in[3];
  const float* sstate = (const float*)d_in[4];
  const int*   rows   = (const int*)d_in[5];
  const int*   cols   = (const int*)d_in[6];
  const int    nc     = in_sizes[3];
  float* out = (float*)d_out;
  float* ws  = (float*)d_ws;

  float*    a    = ws;                              // 32768 floats
  float*    thr  = ws + 32768;                      // 16 floats
  unsigned* hist = (unsigned*)(ws + 32784);         // 8192 bins
  int*      acc  = (int*)(ws + 32784 + NBINS);      // 4 ints (sum, cnt, done, hist-done)
  int*      part = (int*)(ws + 32784 + NBINS + 16); // NPB * 8192 ints (8 MB)

  gemm_kernel<<<PP / 8, 256, 0, stream>>>(x, W, bias, a, hist, acc);
  hist_thr_kernel<<<NTOT / 4096, 1024, 0, stream>>>(a, hist, acc, thr);
  spmv_kernel<<<NPB, 1024, 0, stream>>>(vals, rows, cols, a, thr, sstate, part, nc);
  finalize_kernel<<<PP / 32, 256, 0, stream>>>(part, a, thr, sstate, out, acc);
}